// Round 19
// baseline (9683.784 us; speedup 1.0000x reference)
//
#include <hip/hip_runtime.h>
#include <math.h>

#define DT 0.01f
constexpr int T = 512, B = 128, I = 256, H = 1024, O = 256;
constexpr int K = I + H;          // 1280

// ---- workspace layout (float offsets) ----
constexpr size_t OFF_OSUM  = 0;                              // B*H
constexpr size_t OFF_HUH0  = OFF_OSUM + (size_t)B * H;       // bf16 hi plane buf0
constexpr size_t OFF_HUL0  = OFF_HUH0 + (size_t)B * H / 2;
constexpr size_t OFF_HUH1  = OFF_HUL0 + (size_t)B * H / 2;
constexpr size_t OFF_HUL1  = OFF_HUH1 + (size_t)B * H / 2;
constexpr size_t OFF_COEF  = OFF_HUL1 + (size_t)B * H / 2;   // k1,k2,k3,al,1-al
// flags: fast[0,1024) compact; safe[1024,1024+16384) stride-16; ctr[17408,17416)
constexpr size_t OFF_FLAGS = OFF_COEF + 5 * (size_t)H;
constexpr size_t OFF_WHH   = OFF_FLAGS + 17424;
constexpr size_t OFF_WHL   = OFF_WHH + 64 * 40 * 64 * 8 / 2;
constexpr size_t OFF_WOH   = OFF_WHL + 64 * 40 * 64 * 8 / 2;
constexpr size_t OFF_WOL   = OFF_WOH + 64 * 32 * 64 * 8 / 2;

// ---- LDS layout (bytes) ----
constexpr int SM_WHH  = 0;        // W_h-hi hu-part [2 cg][32 ks][64] short8 = 65536
constexpr int SM_WHL  = 65536;    // W_h-lo hu-part = 65536
constexpr int SM_REDS = 131072;   // [4 ksl][16][33] f32 = 8448
constexpr int SM_REDP = 139520;   // 8448
constexpr int SM_BYTES = 147968;  // > 81920 -> 1 WG/CU -> 32 WGs/XCD (pigeonhole)

typedef __attribute__((ext_vector_type(8))) short short8v;
typedef __attribute__((ext_vector_type(4))) float f32x4;

static __device__ inline short f2bf(float f) {               // RTN-even fp32->bf16
    unsigned u = __builtin_bit_cast(unsigned, f);
    u += 0x7fffu + ((u >> 16) & 1u);
    return (short)(u >> 16);
}
static __device__ inline float bf2f(short s) {
    return __builtin_bit_cast(float, ((unsigned)(unsigned short)s) << 16);
}

__global__ __launch_bounds__(256)
void init_kernel(float* __restrict__ ws, const float* __restrict__ omega,
                 const float* __restrict__ b_offset, const float* __restrict__ tau_mem,
                 const float* __restrict__ gain) {
    size_t tid = (size_t)blockIdx.x * blockDim.x + threadIdx.x;
    size_t stride = (size_t)gridDim.x * blockDim.x;
    for (size_t i = tid; i < (size_t)B * H; i += stride) ws[OFF_HUH0 + i] = 0.0f;
    for (size_t i = tid; i < 17424; i += stride) ws[OFF_FLAGS + i] = 0.0f;  // flags + ctr
    if (tid < H) {
        float om  = fabsf(omega[tid]);
        float om2 = om * om;
        float bb  = om2 * 0.005f + fabsf(b_offset[tid]);
        float al  = expf(-1.0f / fabsf(tau_mem[tid]));
        float g   = gain[tid];
        ws[OFF_COEF + 0 * H + tid] = g * (1.0f - 2.0f * bb * DT);  // k1
        ws[OFF_COEF + 1 * H + tid] = g * DT;                       // k2
        ws[OFF_COEF + 2 * H + tid] = g * om2 * DT;                 // k3
        ws[OFF_COEF + 3 * H + tid] = al;                           // alpha
        ws[OFF_COEF + 4 * H + tid] = 1.0f - al;
    }
}

// W [N x Kd] fp32 -> bf16 hi/lo in MFMA B-fragment order (validated r4-r18).
template <int NKS, int KD>
__global__ __launch_bounds__(256)
void convert_kernel(const float* __restrict__ W, short* __restrict__ WH,
                    short* __restrict__ WL) {
    int g = blockIdx.x * 256 + threadIdx.x;
    int lane = g & 63;
    int ks = (g >> 6) % NKS;
    int cg = g / (NKS * 64);
    int col = cg * 16 + (lane & 15);
    int k = ks * 32 + ((lane >> 4) << 3);
    const float* src = W + (size_t)col * KD + k;
    short8v hi, lo;
    #pragma unroll
    for (int j = 0; j < 8; ++j) {
        float v = src[j];
        short h = f2bf(v);
        hi[j] = h;
        lo[j] = f2bf(v - bf2f(h));
    }
    *(short8v*)(WH + (size_t)g * 8) = hi;
    *(short8v*)(WL + (size_t)g * 8) = lo;
}

// dual-path poll: fast sc0 L2 flag + agent-atomic LLC backstop (r13-proven)
static __device__ inline void poll_ge(const int* fastp, int* safep, int s) {
    int v, spins = 0;
    for (;;) {
        asm volatile("global_load_dword %0, %1, off sc0\n\ts_waitcnt vmcnt(0)"
                     : "=v"(v) : "v"(fastp) : "memory");
        if (v >= s) break;
        if ((++spins & 63) == 0) {
            v = __hip_atomic_load(safep, __ATOMIC_RELAXED, __HIP_MEMORY_SCOPE_AGENT);
            if (v >= s) break;
        }
        __builtin_amdgcn_s_sleep(1);
    }
}

// Persistent RNN v15 = r18 champion + flag path off the rendezvous & off the LLC:
//  - PER-WAVE publish flags (4/WG, rows 4w..4w+3), set right after the wave's own
//    vmcnt(0) drain, BEFORE sync3 (sync3 kept only for intra-WG LDS reuse order).
//  - Dual-path flags: fast sc0 (XCD-L2, same path as hu data) + agent backstop.
//  - DATA poll: lanes 0-31/wave poll 32 producer wave-flags (8 prod x 4 waves).
//  - CLOBBER gate: tid<32 polls wave-0 flag of each WG (any wave-flag >= s
//    implies that WG passed sync2(s-1) => its plane reads done).
__global__ __launch_bounds__(512)
void rnn_persist(const float* __restrict__ x, float* __restrict__ ws) {
    extern __shared__ char sm[];
    float* redS = (float*)(sm + SM_REDS);
    float* redP = (float*)(sm + SM_REDP);
    __shared__ int role_sm;

    const float* coef = ws + OFF_COEF;
    float* osum_g = ws + OFF_OSUM;
    const short* huhS[2] = {(const short*)(ws + OFF_HUH0), (const short*)(ws + OFF_HUH1)};
    const short* hulS[2] = {(const short*)(ws + OFF_HUL0), (const short*)(ws + OFF_HUL1)};
    unsigned int* huhW[2] = {(unsigned int*)(ws + OFF_HUH0), (unsigned int*)(ws + OFF_HUH1)};
    unsigned int* hulW[2] = {(unsigned int*)(ws + OFF_HUL0), (unsigned int*)(ws + OFF_HUL1)};
    int* fastF = (int*)(ws + OFF_FLAGS);          // [xcc*128 + g*4 + w]
    int* safeF = fastF + 1024;                    // same idx * 16
    int* ctr   = fastF + 17408;

    const int tid = threadIdx.x;

    // ---- dynamic role claim: physical XCD id + per-XCD slot (r11-validated) ----
    if (tid == 0) {
        unsigned xcc_;
        asm volatile("s_getreg_b32 %0, hwreg(HW_REG_XCC_ID)" : "=s"(xcc_));
        int slot = atomicAdd(ctr + (xcc_ & 7), 1);
        role_sm = (int)((xcc_ & 7) * 32 + (slot & 31));
    }
    __syncthreads();
    const int role = role_sm;
    const int xcc = role >> 5;        // row-group = this physical XCD
    const int g   = role & 31;        // col32grp
    const int col0 = g * 32, row0 = xcc * 16;

    const int wid = tid >> 6, lane = tid & 63;
    const int ntile = wid & 1, ksl = wid >> 1;   // 2 ntiles x 4 kslices
    const int colgrp = 2 * g + ntile;
    const int rowg = row0 + (lane & 15);
    const int koff = (lane >> 4) << 3;

    // ---- stage W_h hu-part (hi+lo) into LDS (once) ----
    {
        const float4* srcH = (const float4*)(ws + OFF_WHH);
        const float4* srcL = (const float4*)(ws + OFF_WHL);
        float4* dH = (float4*)(sm + SM_WHH);
        float4* dL = (float4*)(sm + SM_WHL);
        for (int i = tid; i < 2 * 2048; i += 512) {
            int n = i >> 11, rem = i & 2047;
            dH[i] = srcH[((size_t)(2 * g + n) * 40 + 8) * 64 + rem];
            dL[i] = srcL[((size_t)(2 * g + n) * 40 + 8) * 64 + rem];
        }
    }
    // ---- pin step-invariant weights in registers ----
    short8v woh[8], wxh[2], wxl[2];
    {
        const short8v* WOHg = (const short8v*)(ws + OFF_WOH) + (size_t)colgrp * 32 * 64 + lane;
        const short8v* WXH  = (const short8v*)(ws + OFF_WHH) + (size_t)colgrp * 40 * 64 + lane;
        const short8v* WXL  = (const short8v*)(ws + OFF_WHL) + (size_t)colgrp * 40 * 64 + lane;
        #pragma unroll
        for (int j = 0; j < 8; ++j) woh[j] = WOHg[(ksl * 8 + j) * 64];
        #pragma unroll
        for (int j = 0; j < 2; ++j) { wxh[j] = WXH[(ksl * 2 + j) * 64]; wxl[j] = WXL[(ksl * 2 + j) * 64]; }
    }
    __syncthreads();

    const short8v* lWHH = (const short8v*)(sm + SM_WHH) + (size_t)ntile * 2048 + lane;
    const short8v* lWHL = (const short8v*)(sm + SM_WHL) + (size_t)ntile * 2048 + lane;

    // epilogue ownership (tid<256): wave w owns rows 4w..4w+3; er = tid>>4
    const int er = tid >> 4;
    const int ec0 = (tid & 15) * 2;
    const int gcol0 = col0 + ec0;
    const size_t erow = (size_t)(row0 + (er & 15));
    float k1a=0,k1b=0,k2a=0,k2b=0,k3a=0,k3b=0, ala=0,alb=0,alma=0,almb=0;
    if (tid < 256) {
        k1a = coef[gcol0];         k1b = coef[gcol0 + 1];
        k2a = coef[H + gcol0];     k2b = coef[H + gcol0 + 1];
        k3a = coef[2 * H + gcol0]; k3b = coef[2 * H + gcol0 + 1];
        ala = coef[3 * H + gcol0]; alb = coef[3 * H + gcol0 + 1];
        alma = coef[4 * H + gcol0]; almb = coef[4 * H + gcol0 + 1];
    }
    float hva=0,hvb=0,oua=0,oub=0,osa=0,osb=0,hua=0,hub=0;

    // flag pointers
    int* myfast = fastF + (xcc * 128 + g * 4 + wid);                 // waves 0..3 publish
    int* mysafe = safeF + ((xcc * 128 + g * 4 + wid) << 4);
    // data poll: this wave reads cols [256*ksl,256*ksl+256) <- producers 8*ksl..8*ksl+7, all 4 waves
    const int didx = xcc * 128 + (8 * ksl + (lane >> 2)) * 4 + (lane & 3);
    const int* dfast = fastF + didx;
    int* dsafe = safeF + (didx << 4);
    // clobber poll: wave-0 flag of WG (tid)
    const int cidx = xcc * 128 + tid * 4;
    const int* cfast = fastF + cidx;
    int* csafe = safeF + (cidx << 4);

    const size_t rowOffH = (size_t)rowg * H + koff;

    for (int s = 0; s <= T; ++s) {
        const bool last = (s == T);
        f32x4 accS = {0, 0, 0, 0}, accP = {0, 0, 0, 0};

        // ---- A: pre-poll x-part S-GEMM (weights pinned; x cached loads) ----
        if (!last) {
            const float* xrow = x + (size_t)s * B * I + (size_t)rowg * I + koff;
            #pragma unroll
            for (int j = 0; j < 2; ++j) {
                float4 a0 = *(const float4*)(xrow + (ksl * 2 + j) * 32);
                float4 a1 = *(const float4*)(xrow + (ksl * 2 + j) * 32 + 4);
                float av[8] = {a0.x,a0.y,a0.z,a0.w,a1.x,a1.y,a1.z,a1.w};
                short8v ah, alv;
                #pragma unroll
                for (int q = 0; q < 8; ++q) {
                    short h = f2bf(av[q]);
                    ah[q] = h;
                    alv[q] = f2bf(av[q] - bf2f(h));
                }
                accS = __builtin_amdgcn_mfma_f32_16x16x32_bf16(ah, wxh[j], accS, 0,0,0);
                accS = __builtin_amdgcn_mfma_f32_16x16x32_bf16(alv, wxh[j], accS, 0,0,0);
                accS = __builtin_amdgcn_mfma_f32_16x16x32_bf16(ah, wxl[j], accS, 0,0,0);
            }
        }

        // ---- B': per-wave DATA poll (32 producer wave-flags, dual-path) ----
        if (lane < 32) poll_ge(dfast, dsafe, s);
        asm volatile("" ::: "memory");

        // ---- C: hu loads sc0 (XCD-L2) + S-GEMM (counted vmcnt) ----
        const short* hb_ = huhS[s & 1] + rowOffH;
        const short* lb_ = hulS[s & 1] + rowOffH;
        short8v hbuf[8], lbuf[8];
        #pragma unroll
        for (int j = 0; j < 8; ++j) {
            asm volatile("global_load_dwordx4 %0, %1, off sc0" : "=v"(hbuf[j]) : "v"(hb_ + (ksl * 8 + j) * 32));
            asm volatile("global_load_dwordx4 %0, %1, off sc0" : "=v"(lbuf[j]) : "v"(lb_ + (ksl * 8 + j) * 32));
        }

        if (!last) {
            asm volatile("s_waitcnt vmcnt(8)");
            __builtin_amdgcn_sched_barrier(0);
            #pragma unroll
            for (int j = 0; j < 4; ++j) {
                short8v ch = lWHH[(ksl * 8 + j) * 64];
                short8v cl = lWHL[(ksl * 8 + j) * 64];
                accS = __builtin_amdgcn_mfma_f32_16x16x32_bf16(hbuf[j], ch, accS, 0,0,0);
                accS = __builtin_amdgcn_mfma_f32_16x16x32_bf16(lbuf[j], ch, accS, 0,0,0);
                accS = __builtin_amdgcn_mfma_f32_16x16x32_bf16(hbuf[j], cl, accS, 0,0,0);
            }
            asm volatile("s_waitcnt vmcnt(0)");
            __builtin_amdgcn_sched_barrier(0);
            #pragma unroll
            for (int j = 4; j < 8; ++j) {
                short8v ch = lWHH[(ksl * 8 + j) * 64];
                short8v cl = lWHL[(ksl * 8 + j) * 64];
                accS = __builtin_amdgcn_mfma_f32_16x16x32_bf16(hbuf[j], ch, accS, 0,0,0);
                accS = __builtin_amdgcn_mfma_f32_16x16x32_bf16(lbuf[j], ch, accS, 0,0,0);
                accS = __builtin_amdgcn_mfma_f32_16x16x32_bf16(hbuf[j], cl, accS, 0,0,0);
            }
            // C/D layout: col = lane&15, row = (lane>>4)*4 + r   [HW-verified]
            #pragma unroll
            for (int r = 0; r < 4; ++r) {
                int crow = ((lane >> 4) << 2) + r;
                redS[ksl * 528 + crow * 33 + ntile * 16 + (lane & 15)] = accS[r];
            }
        } else {
            asm volatile("s_waitcnt vmcnt(0)");
            __builtin_amdgcn_sched_barrier(0);
        }

        // ---- CLOBBER gate (hidden behind S-GEMM; dual-path) ----
        if (tid < 32) poll_ge(cfast, csafe, s);
        __syncthreads();   // sync2
        asm volatile("" ::: "memory");

        // ---- D: LI-epi of s-1 (redP) + S-epi -> hu update -> publish ----
        if (s > 0 && tid < 256) {
            const float* rp = redP + er * 33 + ec0;
            float p0 = (rp[0] + rp[528]) + (rp[1056] + rp[1584]);
            float p1 = (rp[1] + rp[529]) + (rp[1057] + rp[1585]);
            oua = oua * ala + p0 * alma; osa += oua;
            oub = oub * alb + p1 * almb; osb += oub;
        }
        if (!last) {
            if (tid < 256) {
                const float* rs = redS + er * 33 + ec0;
                float s0 = (rs[0] + rs[528]) + (rs[1056] + rs[1584]);
                float s1 = (rs[1] + rs[529]) + (rs[1057] + rs[1585]);
                float hvn0 = hva + hua * DT;
                float hun0 = k1a * hua + k2a * s0 - k3a * hvn0;
                hva = hvn0; hua = hun0;
                float hvn1 = hvb + hub * DT;
                float hun1 = k1b * hub + k2b * s1 - k3b * hvn1;
                hvb = hvn1; hub = hun1;
                short h0 = f2bf(hun0), h1 = f2bf(hun1);
                short l0 = f2bf(hun0 - bf2f(h0)), l1 = f2bf(hun1 - bf2f(h1));
                unsigned hp = (unsigned)(unsigned short)h0 | ((unsigned)(unsigned short)h1 << 16);
                unsigned lp = (unsigned)(unsigned short)l0 | ((unsigned)(unsigned short)l1 << 16);
                size_t off32 = (erow * H + gcol0) >> 1;
                unsigned int* hp_ = huhW[(s + 1) & 1] + off32;
                unsigned int* lp_ = hulW[(s + 1) & 1] + off32;
                asm volatile("global_store_dword %0, %1, off sc0" :: "v"(hp_), "v"(hp) : "memory");
                asm volatile("global_store_dword %0, %1, off sc0" :: "v"(lp_), "v"(lp) : "memory");
                // per-wave drain + flag (BEFORE sync3: off the inter-WG chain)
                asm volatile("s_waitcnt vmcnt(0)" ::: "memory");
                if ((tid & 63) == 0) {
                    int fv = s + 1;
                    asm volatile("global_store_dword %0, %1, off sc0" :: "v"(myfast), "v"(fv) : "memory");
                    __hip_atomic_store(mysafe, fv, __ATOMIC_RELAXED, __HIP_MEMORY_SCOPE_AGENT);
                }
            }
            __syncthreads();   // sync3: intra-WG order (redS/redP reuse) only
        } else {
            __syncthreads();   // sync3: order LI-epi redP read vs F's redP write
        }

        // ---- F: P-GEMM (off critical path; W_o-hi pinned in regs) ----
        #pragma unroll
        for (int j = 0; j < 8; ++j) {
            accP = __builtin_amdgcn_mfma_f32_16x16x32_bf16(hbuf[j], woh[j], accP, 0,0,0);
            accP = __builtin_amdgcn_mfma_f32_16x16x32_bf16(lbuf[j], woh[j], accP, 0,0,0);
        }
        #pragma unroll
        for (int r = 0; r < 4; ++r) {
            int crow = ((lane >> 4) << 2) + r;
            redP[ksl * 528 + crow * 33 + ntile * 16 + (lane & 15)] = accP[r];
        }
        // redP consumed after next iteration's sync2 (or final sync below)
    }

    __syncthreads();
    if (tid < 256) {
        const float* rp = redP + er * 33 + ec0;
        float p0 = (rp[0] + rp[528]) + (rp[1056] + rp[1584]);
        float p1 = (rp[1] + rp[529]) + (rp[1057] + rp[1585]);
        float o0 = oua * ala + p0 * alma; osa += o0;
        float o1 = oub * alb + p1 * almb; osb += o1;
        osum_g[erow * H + gcol0] = osa;
        osum_g[erow * H + gcol0 + 1] = osb;
    }
}

// out = osum @ W_out^T + T*b_out  (fp32 scalar, proven round 1)
__global__ __launch_bounds__(256)
void readout_kernel(const float* __restrict__ ou_sum, const float* __restrict__ W_out,
                    const float* __restrict__ b_out, float* __restrict__ out) {
    constexpr int KC = 128, BT = 32, CT = 16;
    __shared__ float act[BT][KC + 4];
    __shared__ float w[CT][KC + 4];
    int wg = blockIdx.x;
    int bt = wg & 3, cg = wg >> 2;
    int row0 = bt * BT, col0 = cg * CT;
    int tid = threadIdx.x;
    int c = tid & 15, rr = tid >> 4;

    float4 acc0 = {0, 0, 0, 0}, acc1 = {0, 0, 0, 0};
    for (int kc = 0; kc < H / KC; ++kc) {
        int k0 = kc * KC;
        for (int i = tid; i < BT * (KC / 4); i += 256) {
            int r = i >> 5, c4 = (i & 31) * 4;
            *(float4*)&act[r][c4] = *(const float4*)&ou_sum[(size_t)(row0 + r) * H + k0 + c4];
        }
        for (int i = tid; i < CT * (KC / 4); i += 256) {
            int r = i >> 5, c4 = (i & 31) * 4;
            *(float4*)&w[r][c4] = *(const float4*)&W_out[(size_t)(col0 + r) * H + k0 + c4];
        }
        __syncthreads();
        #pragma unroll
        for (int k4 = 0; k4 < KC / 4; ++k4) {
            float4 a0 = *(const float4*)&act[rr][k4 * 4];
            float4 a1 = *(const float4*)&act[rr + 16][k4 * 4];
            float4 w0 = *(const float4*)&w[c][k4 * 4];
            acc0.x = fmaf(a0.x, w0.x, acc0.x); acc0.y = fmaf(a0.y, w0.y, acc0.y);
            acc0.z = fmaf(a0.z, w0.z, acc0.z); acc0.w = fmaf(a0.w, w0.w, acc0.w);
            acc1.x = fmaf(a1.x, w0.x, acc1.x); acc1.y = fmaf(a1.y, w0.y, acc1.y);
            acc1.z = fmaf(a1.z, w0.z, acc1.z); acc1.w = fmaf(a1.w, w0.w, acc1.w);
        }
        __syncthreads();
    }
    float v0 = (acc0.x + acc0.y) + (acc0.z + acc0.w);
    float v1 = (acc1.x + acc1.y) + (acc1.z + acc1.w);
    int gcol = col0 + c;
    float bo = b_out[gcol] * (float)T;
    out[(size_t)(row0 + rr) * O + gcol] = v0 + bo;
    out[(size_t)(row0 + rr + 16) * O + gcol] = v1 + bo;
}

extern "C" void kernel_launch(void* const* d_in, const int* in_sizes, int n_in,
                              void* d_out, int out_size, void* d_ws, size_t ws_size,
                              hipStream_t stream) {
    const float* x        = (const float*)d_in[0];
    const float* W_h      = (const float*)d_in[1];
    const float* gain     = (const float*)d_in[2];
    const float* omega    = (const float*)d_in[3];
    const float* b_offset = (const float*)d_in[4];
    const float* W_o      = (const float*)d_in[5];
    const float* tau_mem  = (const float*)d_in[6];
    const float* W_out    = (const float*)d_in[7];
    const float* b_out    = (const float*)d_in[8];
    float* ws  = (float*)d_ws;
    float* out = (float*)d_out;

    init_kernel<<<512, 256, 0, stream>>>(ws, omega, b_offset, tau_mem, gain);
    convert_kernel<40, K><<<640, 256, 0, stream>>>(
        W_h, (short*)(ws + OFF_WHH), (short*)(ws + OFF_WHL));
    convert_kernel<32, H><<<512, 256, 0, stream>>>(
        W_o, (short*)(ws + OFF_WOH), (short*)(ws + OFF_WOL));

    rnn_persist<<<256, 512, SM_BYTES, stream>>>(x, ws);

    readout_kernel<<<64, 256, 0, stream>>>(ws + OFF_OSUM, W_out, b_out, out);
}

// Round 20
// 3279.750 us; speedup vs baseline: 2.9526x; 2.9526x over previous
//
#include <hip/hip_runtime.h>
#include <math.h>

#define DT 0.01f
constexpr int T = 512, B = 128, I = 256, H = 1024, O = 256;
constexpr int K = I + H;          // 1280

// ---- workspace layout (float offsets) ----
constexpr size_t OFF_OSUM  = 0;                              // B*H
constexpr size_t OFF_HUH0  = OFF_OSUM + (size_t)B * H;       // bf16 hi plane buf0
constexpr size_t OFF_HUL0  = OFF_HUH0 + (size_t)B * H / 2;
constexpr size_t OFF_HUH1  = OFF_HUL0 + (size_t)B * H / 2;
constexpr size_t OFF_HUL1  = OFF_HUH1 + (size_t)B * H / 2;
constexpr size_t OFF_COEF  = OFF_HUL1 + (size_t)B * H / 2;   // k1,k2,k3,al,1-al
constexpr size_t OFF_FLAGS = OFF_COEF + 5 * (size_t)H;       // 8192 ints (flags + ctr)
constexpr size_t OFF_WHH   = OFF_FLAGS + 8192;
constexpr size_t OFF_WHL   = OFF_WHH + 64 * 40 * 64 * 8 / 2;
constexpr size_t OFF_WOH   = OFF_WHL + 64 * 40 * 64 * 8 / 2;
constexpr size_t OFF_WOL   = OFF_WOH + 64 * 32 * 64 * 8 / 2;

// ---- LDS layout (bytes) ----
constexpr int SM_WHH  = 0;        // W_h-hi hu-part [2 cg][32 ks][64] short8 = 65536
constexpr int SM_WHL  = 65536;    // W_h-lo hu-part = 65536
constexpr int SM_REDS = 131072;   // [4 ksl][16][33] f32 = 8448
constexpr int SM_REDP = 139520;   // 8448
constexpr int SM_BYTES = 147968;  // > 81920 -> 1 WG/CU -> 32 WGs/XCD (pigeonhole)

typedef __attribute__((ext_vector_type(8))) short short8v;
typedef __attribute__((ext_vector_type(4))) float f32x4;

static __device__ inline short f2bf(float f) {               // RTN-even fp32->bf16
    unsigned u = __builtin_bit_cast(unsigned, f);
    u += 0x7fffu + ((u >> 16) & 1u);
    return (short)(u >> 16);
}
static __device__ inline float bf2f(short s) {
    return __builtin_bit_cast(float, ((unsigned)(unsigned short)s) << 16);
}

__global__ __launch_bounds__(256)
void init_kernel(float* __restrict__ ws, const float* __restrict__ omega,
                 const float* __restrict__ b_offset, const float* __restrict__ tau_mem,
                 const float* __restrict__ gain) {
    size_t tid = (size_t)blockIdx.x * blockDim.x + threadIdx.x;
    size_t stride = (size_t)gridDim.x * blockDim.x;
    for (size_t i = tid; i < (size_t)B * H; i += stride) ws[OFF_HUH0 + i] = 0.0f;
    for (size_t i = tid; i < 8192; i += stride) ws[OFF_FLAGS + i] = 0.0f;  // flags + role ctr
    if (tid < H) {
        float om  = fabsf(omega[tid]);
        float om2 = om * om;
        float bb  = om2 * 0.005f + fabsf(b_offset[tid]);
        float al  = expf(-1.0f / fabsf(tau_mem[tid]));
        float g   = gain[tid];
        ws[OFF_COEF + 0 * H + tid] = g * (1.0f - 2.0f * bb * DT);  // k1
        ws[OFF_COEF + 1 * H + tid] = g * DT;                       // k2
        ws[OFF_COEF + 2 * H + tid] = g * om2 * DT;                 // k3
        ws[OFF_COEF + 3 * H + tid] = al;                           // alpha
        ws[OFF_COEF + 4 * H + tid] = 1.0f - al;
    }
}

// W [N x Kd] fp32 -> bf16 hi/lo in MFMA B-fragment order (validated r4-r18).
template <int NKS, int KD>
__global__ __launch_bounds__(256)
void convert_kernel(const float* __restrict__ W, short* __restrict__ WH,
                    short* __restrict__ WL) {
    int g = blockIdx.x * 256 + threadIdx.x;
    int lane = g & 63;
    int ks = (g >> 6) % NKS;
    int cg = g / (NKS * 64);
    int col = cg * 16 + (lane & 15);
    int k = ks * 32 + ((lane >> 4) << 3);
    const float* src = W + (size_t)col * KD + k;
    short8v hi, lo;
    #pragma unroll
    for (int j = 0; j < 8; ++j) {
        float v = src[j];
        short h = f2bf(v);
        hi[j] = h;
        lo[j] = f2bf(v - bf2f(h));
    }
    *(short8v*)(WH + (size_t)g * 8) = hi;
    *(short8v*)(WL + (size_t)g * 8) = lo;
}

// Persistent RNN v14 (r18 champion): r11 XCD-local pipelines + refined wait graph:
//  - DATA wait: per-wave poll of the 8 producers whose columns this wave reads
//    (cols [256*ksl, 256*ksl+256) <- producers g in [8*ksl, 8*ksl+8)). Waves
//    start loads/MFMAs staggered; no WG-wide sync before compute.
//  - CLOBBER gate (plane (s+1)&1 free: all 32 readers' flags >= s) AFTER the
//    S-GEMM (hidden behind compute), checked by tid<32 just before sync2.
//  Barrier audit: redS W(C,pre-sync2)->R(D,post-sync2) ok; redP W(F,s-1)->R(D,s)
//  ordered by sync2(s); R(D,s)->W(F,s) ordered by sync3(s). Publish ordered
//  after clobber-poll+sync2; flag after vmcnt(0)+sync3 (r11 semantics).
//  Flags: agent-scope LLC atomics + s_sleep (the ONLY spin primitive that works
//  on this fabric — sc0-poll variants hang (r12) or regress 3x (r19)).
__global__ __launch_bounds__(512)
void rnn_persist(const float* __restrict__ x, float* __restrict__ ws) {
    extern __shared__ char sm[];
    float* redS = (float*)(sm + SM_REDS);
    float* redP = (float*)(sm + SM_REDP);
    __shared__ int role_sm;

    const float* coef = ws + OFF_COEF;
    float* osum_g = ws + OFF_OSUM;
    const short* huhS[2] = {(const short*)(ws + OFF_HUH0), (const short*)(ws + OFF_HUH1)};
    const short* hulS[2] = {(const short*)(ws + OFF_HUL0), (const short*)(ws + OFF_HUL1)};
    unsigned int* huhW[2] = {(unsigned int*)(ws + OFF_HUH0), (unsigned int*)(ws + OFF_HUH1)};
    unsigned int* hulW[2] = {(unsigned int*)(ws + OFF_HUL0), (unsigned int*)(ws + OFF_HUL1)};
    int* flags = (int*)(ws + OFF_FLAGS);
    int* ctr   = flags + 4096;

    const int tid = threadIdx.x;

    // ---- dynamic role claim: physical XCD id + per-XCD slot (r11-validated) ----
    if (tid == 0) {
        unsigned xcc_;
        asm volatile("s_getreg_b32 %0, hwreg(HW_REG_XCC_ID)" : "=s"(xcc_));
        int slot = atomicAdd(ctr + (xcc_ & 7), 1);
        role_sm = (int)((xcc_ & 7) * 32 + (slot & 31));
    }
    __syncthreads();
    const int role = role_sm;
    const int xcc = role >> 5;        // row-group = this physical XCD
    const int g   = role & 31;        // col32grp
    const int col0 = g * 32, row0 = xcc * 16;

    const int wid = tid >> 6, lane = tid & 63;
    const int ntile = wid & 1, ksl = wid >> 1;   // 2 ntiles x 4 kslices
    const int colgrp = 2 * g + ntile;
    const int rowg = row0 + (lane & 15);
    const int koff = (lane >> 4) << 3;

    // ---- stage W_h hu-part (hi+lo) into LDS (once) ----
    {
        const float4* srcH = (const float4*)(ws + OFF_WHH);
        const float4* srcL = (const float4*)(ws + OFF_WHL);
        float4* dH = (float4*)(sm + SM_WHH);
        float4* dL = (float4*)(sm + SM_WHL);
        for (int i = tid; i < 2 * 2048; i += 512) {
            int n = i >> 11, rem = i & 2047;
            dH[i] = srcH[((size_t)(2 * g + n) * 40 + 8) * 64 + rem];
            dL[i] = srcL[((size_t)(2 * g + n) * 40 + 8) * 64 + rem];
        }
    }
    // ---- pin step-invariant weights in registers ----
    short8v woh[8], wxh[2], wxl[2];
    {
        const short8v* WOHg = (const short8v*)(ws + OFF_WOH) + (size_t)colgrp * 32 * 64 + lane;
        const short8v* WXH  = (const short8v*)(ws + OFF_WHH) + (size_t)colgrp * 40 * 64 + lane;
        const short8v* WXL  = (const short8v*)(ws + OFF_WHL) + (size_t)colgrp * 40 * 64 + lane;
        #pragma unroll
        for (int j = 0; j < 8; ++j) woh[j] = WOHg[(ksl * 8 + j) * 64];
        #pragma unroll
        for (int j = 0; j < 2; ++j) { wxh[j] = WXH[(ksl * 2 + j) * 64]; wxl[j] = WXL[(ksl * 2 + j) * 64]; }
    }
    __syncthreads();

    const short8v* lWHH = (const short8v*)(sm + SM_WHH) + (size_t)ntile * 2048 + lane;
    const short8v* lWHL = (const short8v*)(sm + SM_WHL) + (size_t)ntile * 2048 + lane;

    // epilogue ownership (tid<256): row er (0..15), col pair
    const int er = tid >> 4;
    const int ec0 = (tid & 15) * 2;
    const int gcol0 = col0 + ec0;
    const size_t erow = (size_t)(row0 + (er & 15));
    float k1a=0,k1b=0,k2a=0,k2b=0,k3a=0,k3b=0, ala=0,alb=0,alma=0,almb=0;
    if (tid < 256) {
        k1a = coef[gcol0];         k1b = coef[gcol0 + 1];
        k2a = coef[H + gcol0];     k2b = coef[H + gcol0 + 1];
        k3a = coef[2 * H + gcol0]; k3b = coef[2 * H + gcol0 + 1];
        ala = coef[3 * H + gcol0]; alb = coef[3 * H + gcol0 + 1];
        alma = coef[4 * H + gcol0]; almb = coef[4 * H + gcol0 + 1];
    }
    float hva=0,hvb=0,oua=0,oub=0,osa=0,osb=0,hua=0,hub=0;

    int* myflag = flags + ((xcc * 32 + g) << 4);
    int* dpoll  = flags + ((xcc * 32 + (ksl << 3) + (lane & 7)) << 4);  // this wave's 8 producers
    const size_t rowOffH = (size_t)rowg * H + koff;

    for (int s = 0; s <= T; ++s) {
        const bool last = (s == T);
        f32x4 accS = {0, 0, 0, 0}, accP = {0, 0, 0, 0};

        // ---- A: pre-poll x-part S-GEMM (weights pinned; x cached loads) ----
        if (!last) {
            const float* xrow = x + (size_t)s * B * I + (size_t)rowg * I + koff;
            #pragma unroll
            for (int j = 0; j < 2; ++j) {
                float4 a0 = *(const float4*)(xrow + (ksl * 2 + j) * 32);
                float4 a1 = *(const float4*)(xrow + (ksl * 2 + j) * 32 + 4);
                float av[8] = {a0.x,a0.y,a0.z,a0.w,a1.x,a1.y,a1.z,a1.w};
                short8v ah, alv;
                #pragma unroll
                for (int q = 0; q < 8; ++q) {
                    short h = f2bf(av[q]);
                    ah[q] = h;
                    alv[q] = f2bf(av[q] - bf2f(h));
                }
                accS = __builtin_amdgcn_mfma_f32_16x16x32_bf16(ah, wxh[j], accS, 0,0,0);
                accS = __builtin_amdgcn_mfma_f32_16x16x32_bf16(alv, wxh[j], accS, 0,0,0);
                accS = __builtin_amdgcn_mfma_f32_16x16x32_bf16(ah, wxl[j], accS, 0,0,0);
            }
        }

        // ---- B': per-wave DATA poll (only this wave's 8 producers) ----
        while (__hip_atomic_load(dpoll, __ATOMIC_RELAXED, __HIP_MEMORY_SCOPE_AGENT) < s)
            __builtin_amdgcn_s_sleep(1);
        asm volatile("" ::: "memory");

        // ---- C: hu loads sc0 (XCD-L2) + S-GEMM (counted vmcnt) ----
        const short* hb_ = huhS[s & 1] + rowOffH;
        const short* lb_ = hulS[s & 1] + rowOffH;
        short8v hbuf[8], lbuf[8];
        #pragma unroll
        for (int j = 0; j < 8; ++j) {
            asm volatile("global_load_dwordx4 %0, %1, off sc0" : "=v"(hbuf[j]) : "v"(hb_ + (ksl * 8 + j) * 32));
            asm volatile("global_load_dwordx4 %0, %1, off sc0" : "=v"(lbuf[j]) : "v"(lb_ + (ksl * 8 + j) * 32));
        }

        if (!last) {
            asm volatile("s_waitcnt vmcnt(8)");
            __builtin_amdgcn_sched_barrier(0);
            #pragma unroll
            for (int j = 0; j < 4; ++j) {
                short8v ch = lWHH[(ksl * 8 + j) * 64];
                short8v cl = lWHL[(ksl * 8 + j) * 64];
                accS = __builtin_amdgcn_mfma_f32_16x16x32_bf16(hbuf[j], ch, accS, 0,0,0);
                accS = __builtin_amdgcn_mfma_f32_16x16x32_bf16(lbuf[j], ch, accS, 0,0,0);
                accS = __builtin_amdgcn_mfma_f32_16x16x32_bf16(hbuf[j], cl, accS, 0,0,0);
            }
            asm volatile("s_waitcnt vmcnt(0)");
            __builtin_amdgcn_sched_barrier(0);
            #pragma unroll
            for (int j = 4; j < 8; ++j) {
                short8v ch = lWHH[(ksl * 8 + j) * 64];
                short8v cl = lWHL[(ksl * 8 + j) * 64];
                accS = __builtin_amdgcn_mfma_f32_16x16x32_bf16(hbuf[j], ch, accS, 0,0,0);
                accS = __builtin_amdgcn_mfma_f32_16x16x32_bf16(lbuf[j], ch, accS, 0,0,0);
                accS = __builtin_amdgcn_mfma_f32_16x16x32_bf16(hbuf[j], cl, accS, 0,0,0);
            }
            // C/D layout: col = lane&15, row = (lane>>4)*4 + r   [HW-verified]
            #pragma unroll
            for (int r = 0; r < 4; ++r) {
                int crow = ((lane >> 4) << 2) + r;
                redS[ksl * 528 + crow * 33 + ntile * 16 + (lane & 15)] = accS[r];
            }
        } else {
            asm volatile("s_waitcnt vmcnt(0)");
            __builtin_amdgcn_sched_barrier(0);
        }

        // ---- CLOBBER gate: all 32 readers of plane (s+1)&1 are done (flags>=s);
        //      overlapped behind the S-GEMM above, residual wait ~0 ----
        if (tid < 32) {
            int* pollp = flags + ((xcc * 32 + tid) << 4);
            while (__hip_atomic_load(pollp, __ATOMIC_RELAXED, __HIP_MEMORY_SCOPE_AGENT) < s)
                __builtin_amdgcn_s_sleep(1);
        }
        __syncthreads();   // sync2
        asm volatile("" ::: "memory");

        // ---- D: LI-epi of s-1 (redP) + S-epi -> hu update -> publish + flag ----
        if (s > 0 && tid < 256) {
            const float* rp = redP + er * 33 + ec0;
            float p0 = (rp[0] + rp[528]) + (rp[1056] + rp[1584]);
            float p1 = (rp[1] + rp[529]) + (rp[1057] + rp[1585]);
            oua = oua * ala + p0 * alma; osa += oua;
            oub = oub * alb + p1 * almb; osb += oub;
        }
        if (!last) {
            if (tid < 256) {
                const float* rs = redS + er * 33 + ec0;
                float s0 = (rs[0] + rs[528]) + (rs[1056] + rs[1584]);
                float s1 = (rs[1] + rs[529]) + (rs[1057] + rs[1585]);
                float hvn0 = hva + hua * DT;
                float hun0 = k1a * hua + k2a * s0 - k3a * hvn0;
                hva = hvn0; hua = hun0;
                float hvn1 = hvb + hub * DT;
                float hun1 = k1b * hub + k2b * s1 - k3b * hvn1;
                hvb = hvn1; hub = hun1;
                short h0 = f2bf(hun0), h1 = f2bf(hun1);
                short l0 = f2bf(hun0 - bf2f(h0)), l1 = f2bf(hun1 - bf2f(h1));
                unsigned hp = (unsigned)(unsigned short)h0 | ((unsigned)(unsigned short)h1 << 16);
                unsigned lp = (unsigned)(unsigned short)l0 | ((unsigned)(unsigned short)l1 << 16);
                size_t off32 = (erow * H + gcol0) >> 1;
                unsigned int* hp_ = huhW[(s + 1) & 1] + off32;
                unsigned int* lp_ = hulW[(s + 1) & 1] + off32;
                asm volatile("global_store_dword %0, %1, off sc0" :: "v"(hp_), "v"(hp) : "memory");
                asm volatile("global_store_dword %0, %1, off sc0" :: "v"(lp_), "v"(lp) : "memory");
            }
            asm volatile("s_waitcnt vmcnt(0)" ::: "memory");
            __syncthreads();   // sync3
            if (tid == 0)
                __hip_atomic_store(myflag, s + 1, __ATOMIC_RELAXED, __HIP_MEMORY_SCOPE_AGENT);
        } else {
            __syncthreads();   // sync3: order LI-epi redP read vs F's redP write
        }

        // ---- F: P-GEMM (off critical path; W_o-hi pinned in regs) ----
        #pragma unroll
        for (int j = 0; j < 8; ++j) {
            accP = __builtin_amdgcn_mfma_f32_16x16x32_bf16(hbuf[j], woh[j], accP, 0,0,0);
            accP = __builtin_amdgcn_mfma_f32_16x16x32_bf16(lbuf[j], woh[j], accP, 0,0,0);
        }
        #pragma unroll
        for (int r = 0; r < 4; ++r) {
            int crow = ((lane >> 4) << 2) + r;
            redP[ksl * 528 + crow * 33 + ntile * 16 + (lane & 15)] = accP[r];
        }
        // redP consumed after next iteration's sync2 (or final sync below)
    }

    __syncthreads();
    if (tid < 256) {
        const float* rp = redP + er * 33 + ec0;
        float p0 = (rp[0] + rp[528]) + (rp[1056] + rp[1584]);
        float p1 = (rp[1] + rp[529]) + (rp[1057] + rp[1585]);
        float o0 = oua * ala + p0 * alma; osa += o0;
        float o1 = oub * alb + p1 * almb; osb += o1;
        osum_g[erow * H + gcol0] = osa;
        osum_g[erow * H + gcol0 + 1] = osb;
    }
}

// out = osum @ W_out^T + T*b_out  (fp32 scalar, proven round 1)
__global__ __launch_bounds__(256)
void readout_kernel(const float* __restrict__ ou_sum, const float* __restrict__ W_out,
                    const float* __restrict__ b_out, float* __restrict__ out) {
    constexpr int KC = 128, BT = 32, CT = 16;
    __shared__ float act[BT][KC + 4];
    __shared__ float w[CT][KC + 4];
    int wg = blockIdx.x;
    int bt = wg & 3, cg = wg >> 2;
    int row0 = bt * BT, col0 = cg * CT;
    int tid = threadIdx.x;
    int c = tid & 15, rr = tid >> 4;

    float4 acc0 = {0, 0, 0, 0}, acc1 = {0, 0, 0, 0};
    for (int kc = 0; kc < H / KC; ++kc) {
        int k0 = kc * KC;
        for (int i = tid; i < BT * (KC / 4); i += 256) {
            int r = i >> 5, c4 = (i & 31) * 4;
            *(float4*)&act[r][c4] = *(const float4*)&ou_sum[(size_t)(row0 + r) * H + k0 + c4];
        }
        for (int i = tid; i < CT * (KC / 4); i += 256) {
            int r = i >> 5, c4 = (i & 31) * 4;
            *(float4*)&w[r][c4] = *(const float4*)&W_out[(size_t)(col0 + r) * H + k0 + c4];
        }
        __syncthreads();
        #pragma unroll
        for (int k4 = 0; k4 < KC / 4; ++k4) {
            float4 a0 = *(const float4*)&act[rr][k4 * 4];
            float4 a1 = *(const float4*)&act[rr + 16][k4 * 4];
            float4 w0 = *(const float4*)&w[c][k4 * 4];
            acc0.x = fmaf(a0.x, w0.x, acc0.x); acc0.y = fmaf(a0.y, w0.y, acc0.y);
            acc0.z = fmaf(a0.z, w0.z, acc0.z); acc0.w = fmaf(a0.w, w0.w, acc0.w);
            acc1.x = fmaf(a1.x, w0.x, acc1.x); acc1.y = fmaf(a1.y, w0.y, acc1.y);
            acc1.z = fmaf(a1.z, w0.z, acc1.z); acc1.w = fmaf(a1.w, w0.w, acc1.w);
        }
        __syncthreads();
    }
    float v0 = (acc0.x + acc0.y) + (acc0.z + acc0.w);
    float v1 = (acc1.x + acc1.y) + (acc1.z + acc1.w);
    int gcol = col0 + c;
    float bo = b_out[gcol] * (float)T;
    out[(size_t)(row0 + rr) * O + gcol] = v0 + bo;
    out[(size_t)(row0 + rr + 16) * O + gcol] = v1 + bo;
}

extern "C" void kernel_launch(void* const* d_in, const int* in_sizes, int n_in,
                              void* d_out, int out_size, void* d_ws, size_t ws_size,
                              hipStream_t stream) {
    const float* x        = (const float*)d_in[0];
    const float* W_h      = (const float*)d_in[1];
    const float* gain     = (const float*)d_in[2];
    const float* omega    = (const float*)d_in[3];
    const float* b_offset = (const float*)d_in[4];
    const float* W_o      = (const float*)d_in[5];
    const float* tau_mem  = (const float*)d_in[6];
    const float* W_out    = (const float*)d_in[7];
    const float* b_out    = (const float*)d_in[8];
    float* ws  = (float*)d_ws;
    float* out = (float*)d_out;

    init_kernel<<<512, 256, 0, stream>>>(ws, omega, b_offset, tau_mem, gain);
    convert_kernel<40, K><<<640, 256, 0, stream>>>(
        W_h, (short*)(ws + OFF_WHH), (short*)(ws + OFF_WHL));
    convert_kernel<32, H><<<512, 256, 0, stream>>>(
        W_o, (short*)(ws + OFF_WOH), (short*)(ws + OFF_WOL));

    rnn_persist<<<256, 512, SM_BYTES, stream>>>(x, ws);

    readout_kernel<<<64, 256, 0, stream>>>(ws + OFF_OSUM, W_out, b_out, out);
}